// Round 10
// baseline (97.046 us; speedup 1.0000x reference)
//
#include <hip/hip_runtime.h>

#define MDEPTH 5
#define TPB 256
#define LDS_STRIDE 18   // NO pad: block's 18-float rows are contiguous in LDS,
                        // so phase 2 is a straight linear LDS->global copy.

__global__ __launch_bounds__(TPB) void memtap_kernel(
    const float* __restrict__ iq, float* __restrict__ out,
    int B, int S, int T)
{
    const int blocksPerB = (T + TPB - 1) / TPB;
    const int b  = blockIdx.x / blocksPerB;
    const int t0 = (blockIdx.x % blocksPerB) * TPB;
    const int tid = threadIdx.x;

    __shared__ float lds[TPB * LDS_STRIDE];   // 18 KB

    const int t = t0 + tid;
    if (t < T) {
        const int n = t + MDEPTH;                        // n in [5, S-1]
        const float2* iqb = (const float2*)iq + (size_t)b * S;

        float2 v[MDEPTH + 1];
        #pragma unroll
        for (int k = 0; k <= MDEPTH; ++k) v[k] = iqb[n - k];   // v[k] = iq(n-k)

        float* o = &lds[tid * LDS_STRIDE];
        o[0] = v[0].x;                                   // current_iq
        o[1] = v[0].y;
        #pragma unroll
        for (int k = 0; k <= MDEPTH; ++k)                // env(n-k), k=0..5
            o[2 + k] = sqrtf(v[k].x * v[k].x + v[k].y * v[k].y);
        #pragma unroll
        for (int j = 0; j < MDEPTH; ++j) {               // iq(n-1-j), interleaved
            o[8 + 2 * j] = v[j + 1].x;
            o[9 + 2 * j] = v[j + 1].y;
        }
    }
    __syncthreads();

    // Phase 2: linear copy lds[0..nflt) -> out[baseF..baseF+nflt), float4 body.
    // Region base mod 4 is 0 or 2 -> shift 0 or 2 floats; head/tail as float2.
    const int cnt   = min(TPB, T - t0);       // valid rows
    const int nflt  = cnt * 18;               // floats in region (even)
    const size_t baseF = ((size_t)b * T + t0) * 18ull;
    const int shift = (int)(baseF & 3);       // 0 or 2
    const int nq    = (nflt - shift) >> 2;    // aligned float4 stores
    const int tail  = (nflt - shift) & 3;     // 0 or 2

    float* obase = out + baseF;
    for (int g = tid; g < nq; g += TPB) {
        const int F = shift + 4 * g;
        float4 w;
        w.x = lds[F];
        w.y = lds[F + 1];
        w.z = lds[F + 2];
        w.w = lds[F + 3];
        *(float4*)(obase + F) = w;            // (baseF+F)%4==0 -> 16B aligned
    }
    if (tid == 0 && shift) {                  // head 2 floats
        *(float2*)obase = make_float2(lds[0], lds[1]);
    }
    if (tid == 1 && tail) {                   // tail 2 floats
        const int F = nflt - 2;
        *(float2*)(obase + F) = make_float2(lds[F], lds[F + 1]);
    }
}

extern "C" void kernel_launch(void* const* d_in, const int* in_sizes, int n_in,
                              void* d_out, int out_size, void* d_ws, size_t ws_size,
                              hipStream_t stream) {
    (void)in_sizes; (void)n_in; (void)d_ws; (void)ws_size; (void)out_size;
    const float* iq = (const float*)d_in[0];
    float* out = (float*)d_out;

    const int B = 64, S = 16384;
    const int T = S - MDEPTH;                     // 16379
    const int blocksPerB = (T + TPB - 1) / TPB;   // 64
    const int grid = B * blocksPerB;              // 4096

    memtap_kernel<<<grid, TPB, 0, stream>>>(iq, out, B, S, T);
}

// Round 14
// 85.186 us; speedup vs baseline: 1.1392x; 1.1392x over previous
//
#include <hip/hip_runtime.h>

#define MDEPTH 5
#define TPB 256
// Block's rows contiguous in LDS (stride 18 floats) + 2-float front pad for
// the output-alignment shift; all LDS accesses go through a 16B-block XOR
// swizzle (within 128B blocks), so pad LDS to a full 128B multiple:
// max raw byte = 4*(2 + 256*18) = 18440 -> 145 * 128 = 18560 B = 4640 floats.
#define LDS_FLOATS 4640

__device__ __forceinline__ unsigned swz(unsigned b) { return b ^ ((b >> 3) & 0x70u); }

__global__ __launch_bounds__(TPB) void memtap_kernel(
    const float* __restrict__ iq, float* __restrict__ out,
    int B, int S, int T)
{
    const int blocksPerB = (T + TPB - 1) / TPB;
    const int b  = blockIdx.x / blocksPerB;
    const int t0 = (blockIdx.x % blocksPerB) * TPB;
    const int tid = threadIdx.x;

    __shared__ float lds[LDS_FLOATS];
    char* ldsb = (char*)lds;

    const size_t baseF = ((size_t)b * T + t0) * 18ull;   // region base (floats)
    const unsigned shift = (unsigned)(baseF & 3);        // 0 or 2

    const int t = t0 + tid;
    if (t < T) {
        const int n = t + MDEPTH;                        // n in [5, S-1]
        const float2* iqb = (const float2*)iq + ((size_t)b << 14) + n;  // S=16384

        float2 v[6];
        #pragma unroll
        for (int k = 0; k < 6; ++k) v[k] = iqb[-k];      // v[k] = iq(n-k)
        float e[6];
        #pragma unroll
        for (int k = 0; k < 6; ++k) e[k] = sqrtf(v[k].x * v[k].x + v[k].y * v[k].y);

        // Row t lives at LDS float offset shift + 18*tid  (so LDS float idx
        // ≡ output float idx mod 4). 9 swizzled 8B writes, conflict-free.
        const unsigned rb = 4u * (shift + 18u * (unsigned)tid);  // row base byte
        *(float2*)(ldsb + swz(rb     )) = v[0];                          // cols 0,1
        *(float2*)(ldsb + swz(rb + 8 )) = make_float2(e[0], e[1]);       // cols 2,3
        *(float2*)(ldsb + swz(rb + 16)) = make_float2(e[2], e[3]);       // cols 4,5
        *(float2*)(ldsb + swz(rb + 24)) = make_float2(e[4], e[5]);       // cols 6,7
        *(float2*)(ldsb + swz(rb + 32)) = v[1];                          // cols 8,9
        *(float2*)(ldsb + swz(rb + 40)) = v[2];
        *(float2*)(ldsb + swz(rb + 48)) = v[3];
        *(float2*)(ldsb + swz(rb + 56)) = v[4];
        *(float2*)(ldsb + swz(rb + 64)) = v[5];                          // cols 16,17
    }
    __syncthreads();

    // Phase 2: linear copy, swizzled b128 LDS reads -> aligned float4 stores.
    const int cnt  = min(TPB, T - t0);        // valid rows
    const int nflt = cnt * 18;                // region floats (even)
    const int nq   = (nflt - (int)shift) >> 2;

    float* obase = out + baseF;
    for (int g = tid; g < nq; g += TPB) {
        const unsigned x  = shift + 4u * (unsigned)g;   // output float offset
        const unsigned Lb = 4u * (shift + x);           // lds byte (16B-aligned)
        float4 w = *(const float4*)(ldsb + swz(Lb));
        *(float4*)(obase + x) = w;                      // (baseF+x)%4==0
    }
    if (shift && tid == 0) {                  // head floats x=0,1 (L=shift)
        float2 h = *(const float2*)(ldsb + swz(4u * shift));
        *(float2*)obase = h;
    }
    if (((nflt - (int)shift) & 3) && tid == 1) {        // tail 2 floats
        const int x = nflt - 2;
        float2 tl = *(const float2*)(ldsb + swz(4u * (shift + (unsigned)x)));
        *(float2*)(obase + x) = tl;
    }
}

extern "C" void kernel_launch(void* const* d_in, const int* in_sizes, int n_in,
                              void* d_out, int out_size, void* d_ws, size_t ws_size,
                              hipStream_t stream) {
    (void)in_sizes; (void)n_in; (void)d_ws; (void)ws_size; (void)out_size;
    const float* iq = (const float*)d_in[0];
    float* out = (float*)d_out;

    const int B = 64, S = 16384;
    const int T = S - MDEPTH;                     // 16379
    const int blocksPerB = (T + TPB - 1) / TPB;   // 64
    const int grid = B * blocksPerB;              // 4096

    memtap_kernel<<<grid, TPB, 0, stream>>>(iq, out, B, S, T);
}